// Round 1
// baseline (353.886 us; speedup 1.0000x reference)
//
#include <hip/hip_runtime.h>

#define B_ 4
#define T_ 2048
#define D_ 1024
#define HS_ 64

typedef __attribute__((ext_vector_type(4))) float f32x4;
typedef __attribute__((ext_vector_type(8))) short bf16x8;
typedef __attribute__((ext_vector_type(4))) unsigned short u16x4;
typedef __attribute__((ext_vector_type(4))) unsigned int u32x4;

__device__ __forceinline__ unsigned short f2bf(float f) {
  unsigned int u = __float_as_uint(f);
  u += 0x7FFFu + ((u >> 16) & 1u);   // RNE
  return (unsigned short)(u >> 16);
}

// ---------------------------------------------------------------------------
// kconv: build transposed, bf16 hi/lo split weight matrix wT[192][1024].
// cols 0-63 = wq, 64-127 = 8*wk (score scale folded), 128-191 = wv.
// ---------------------------------------------------------------------------
__global__ void kconv_kernel(const float* __restrict__ wq, const float* __restrict__ wk,
                             const float* __restrict__ wv,
                             unsigned short* __restrict__ wTh, unsigned short* __restrict__ wTl) {
  int gid = blockIdx.x * 256 + threadIdx.x;   // < 192*1024
  int n = gid >> 10, d = gid & 1023;
  float v;
  if (n < 64)        v = wq[d * 64 + n];
  else if (n < 128)  v = 8.0f * wk[d * 64 + (n - 64)];
  else               v = wv[d * 64 + (n - 128)];
  unsigned short h = f2bf(v);
  wTh[gid] = h;
  wTl[gid] = f2bf(v - __uint_as_float(((unsigned int)h) << 16));
}

// ---------------------------------------------------------------------------
// kproj: C[8192][192] = x[8192][1024] * wcat via split-bf16 MFMA
// (xh*wh + xh*wl + xl*wh, fp32 accum -> ~fp32 accuracy).
// Outputs: qw fp32 [B][T][64], k8w fp32 [B][T][64] (pre-scaled by 8),
//          vtw bf16 [B][64][T] (transposed V for PV MFMA B-operand).
// ---------------------------------------------------------------------------
__global__ __launch_bounds__(256) void kproj_kernel(
    const float* __restrict__ x, const unsigned short* __restrict__ wTh,
    const unsigned short* __restrict__ wTl,
    const float* __restrict__ bq, const float* __restrict__ bk, const float* __restrict__ bv,
    float* __restrict__ qw, float* __restrict__ k8w, unsigned short* __restrict__ vtw) {
  __shared__ unsigned short xh[32 * 32], xl[32 * 32];     // [row][k] bf16
  __shared__ unsigned short wh[192 * 32], wl[192 * 32];   // [n][k] bf16
  const int tid = threadIdx.x;
  const int m0 = blockIdx.x * 32;
  const int lane = tid & 63, wid = tid >> 6;
  const int mf = wid & 1, np = wid >> 1;
  const int r15 = lane & 15, u = lane >> 4;

  f32x4 xv;
  f32x4 wvh[3], wvl[3];
  auto issue = [&](int k0) {
    xv = *(const f32x4*)&x[(m0 + (tid >> 3)) * 1024 + k0 + (tid & 7) * 4];
#pragma unroll
    for (int i = 0; i < 3; ++i) {
      int c8 = i * 256 + tid;  // 16B chunks of the 192x32 tile
      wvh[i] = *(const f32x4*)&wTh[(c8 >> 2) * 1024 + k0 + (c8 & 3) * 8];
      wvl[i] = *(const f32x4*)&wTl[(c8 >> 2) * 1024 + k0 + (c8 & 3) * 8];
    }
  };
  auto commit = [&]() {
    u16x4 hhv, llv;
#pragma unroll
    for (int c = 0; c < 4; ++c) {
      unsigned short h = f2bf(xv[c]);
      hhv[c] = h;
      llv[c] = f2bf(xv[c] - __uint_as_float(((unsigned int)h) << 16));
    }
    *(u16x4*)&xh[(tid >> 3) * 32 + (tid & 7) * 4] = hhv;
    *(u16x4*)&xl[(tid >> 3) * 32 + (tid & 7) * 4] = llv;
#pragma unroll
    for (int i = 0; i < 3; ++i) {
      int c8 = i * 256 + tid;
      *(f32x4*)&wh[c8 * 8] = wvh[i];
      *(f32x4*)&wl[c8 * 8] = wvl[i];
    }
  };

  f32x4 z = {0.f, 0.f, 0.f, 0.f};
  f32x4 acc[6] = {z, z, z, z, z, z};
  issue(0);
  for (int kt = 0; kt < 32; ++kt) {
    __syncthreads();           // prior compute done before overwrite
    commit();
    __syncthreads();
    if (kt + 1 < 32) issue((kt + 1) * 32);
    bf16x8 ah = *(const bf16x8*)&xh[(mf * 16 + r15) * 32 + u * 8];
    bf16x8 al = *(const bf16x8*)&xl[(mf * 16 + r15) * 32 + u * 8];
#pragma unroll
    for (int nf = 0; nf < 6; ++nf) {
      int nr = np * 96 + nf * 16 + r15;
      bf16x8 bh = *(const bf16x8*)&wh[nr * 32 + u * 8];
      bf16x8 bl = *(const bf16x8*)&wl[nr * 32 + u * 8];
      acc[nf] = __builtin_amdgcn_mfma_f32_16x16x32_bf16(ah, bh, acc[nf], 0, 0, 0);
      acc[nf] = __builtin_amdgcn_mfma_f32_16x16x32_bf16(ah, bl, acc[nf], 0, 0, 0);
      acc[nf] = __builtin_amdgcn_mfma_f32_16x16x32_bf16(al, bh, acc[nf], 0, 0, 0);
    }
  }
  // epilogue: C row = mf*16 + u*4 + r, col = np*96 + nf*16 + r15
#pragma unroll
  for (int nf = 0; nf < 6; ++nf) {
    const int n = np * 96 + nf * 16 + r15;
#pragma unroll
    for (int r = 0; r < 4; ++r) {
      const int m = m0 + mf * 16 + u * 4 + r;
      float val = acc[nf][r];
      if (n < 64) {
        qw[m * 64 + n] = val + bq[n];
      } else if (n < 128) {
        k8w[m * 64 + (n - 64)] = val + 8.0f * bk[n - 64];
      } else {
        int h = n - 128;
        int bb = m >> 11, t = m & 2047;
        vtw[(bb * 64 + h) * 2048 + t] = f2bf(val + bv[h]);
      }
    }
  }
}

// ---------------------------------------------------------------------------
// k1: scores S[b][t][v] = q[b,t,:]·(k8[b,v,:] + rel[t,v,:]), fp32.
// Grid: 256 t-tiles (8 rows) x 2 v-halves. Streams rel (1.07 GB) once.
// LDS rows padded to 68 floats -> conflict-free b128 reads (8 lanes/group).
// ---------------------------------------------------------------------------
__global__ __launch_bounds__(256, 2) void k1_scores(
    const float* __restrict__ qw, const float* __restrict__ k8w,
    const float* __restrict__ rel, float* __restrict__ S) {
  __shared__ float rl[2][64 * 68];   // [(t*8+v)][68]
  __shared__ float kl[2][32 * 68];   // [(b*8+v)][68]
  const int tid = threadIdx.x;
  const int tt = blockIdx.x >> 1, vh = blockIdx.x & 1;
  const int t0 = tt * 8;
  const int vbase = vh * 1024;
  const int wid = tid >> 6;
  const int tl = (tid >> 5) & 1;
  const int vl = (tid >> 2) & 7;
  const int hq = tid & 3;
  const int tloc = wid * 2 + tl;
  const int tg = t0 + tloc;

  // q fragment in registers: 4 batches x 16 h-values (this lane's h-quarter)
  f32x4 qr[4][4];
#pragma unroll
  for (int b = 0; b < 4; ++b)
#pragma unroll
    for (int j = 0; j < 4; ++j)
      qr[b][j] = *(const f32x4*)&qw[((b << 11) + tg) * 64 + hq * 16 + j * 4];

  f32x4 st[6];
  auto issue = [&](int vt) {
#pragma unroll
    for (int i = 0; i < 4; ++i) {              // rel tile: 16KB
      int c4 = i * 256 + tid;
      int pr = c4 >> 4, c = c4 & 15;
      st[i] = *(const f32x4*)&rel[(t0 + (pr >> 3)) * 131072 + (vt + (pr & 7)) * 64 + c * 4];
    }
#pragma unroll
    for (int i = 0; i < 2; ++i) {              // k8 tile: 8KB
      int c4 = i * 256 + tid;
      int pr = c4 >> 4, c = c4 & 15;
      st[4 + i] = *(const f32x4*)&k8w[(pr >> 3) * 131072 + (vt + (pr & 7)) * 64 + c * 4];
    }
  };
  auto commit = [&](int buf) {
#pragma unroll
    for (int i = 0; i < 4; ++i) {
      int c4 = i * 256 + tid;
      int pr = c4 >> 4, c = c4 & 15;
      *(f32x4*)&rl[buf][pr * 68 + c * 4] = st[i];
    }
#pragma unroll
    for (int i = 0; i < 2; ++i) {
      int c4 = i * 256 + tid;
      int pr = c4 >> 4, c = c4 & 15;
      *(f32x4*)&kl[buf][pr * 68 + c * 4] = st[4 + i];
    }
  };

  issue(vbase);
  commit(0);
  __syncthreads();
  int cur = 0;
  for (int it = 0; it < 128; ++it) {
    const int vt = vbase + it * 8;
    if (it + 1 < 128) issue(vt + 8);          // overlap HBM with compute
    f32x4 z = {0.f, 0.f, 0.f, 0.f};
    f32x4 a0 = z, a1 = z, a2 = z, a3 = z;
    const float* rrow = &rl[cur][(tloc * 8 + vl) * 68];
    const float* krow = &kl[cur][vl * 68];
#pragma unroll
    for (int j = 0; j < 4; ++j) {
      int c = (hq * 4 + j) * 4;
      f32x4 r4 = *(const f32x4*)&rrow[c];
      f32x4 kb0 = *(const f32x4*)&krow[c];
      f32x4 kb1 = *(const f32x4*)&krow[544 + c];
      f32x4 kb2 = *(const f32x4*)&krow[1088 + c];
      f32x4 kb3 = *(const f32x4*)&krow[1632 + c];
      a0 += qr[0][j] * (kb0 + r4);
      a1 += qr[1][j] * (kb1 + r4);
      a2 += qr[2][j] * (kb2 + r4);
      a3 += qr[3][j] * (kb3 + r4);
    }
    float s0 = a0[0] + a0[1] + a0[2] + a0[3];
    float s1 = a1[0] + a1[1] + a1[2] + a1[3];
    float s2 = a2[0] + a2[1] + a2[2] + a2[3];
    float s3 = a3[0] + a3[1] + a3[2] + a3[3];
    s0 += __shfl_xor(s0, 1); s0 += __shfl_xor(s0, 2);
    s1 += __shfl_xor(s1, 1); s1 += __shfl_xor(s1, 2);
    s2 += __shfl_xor(s2, 1); s2 += __shfl_xor(s2, 2);
    s3 += __shfl_xor(s3, 1); s3 += __shfl_xor(s3, 2);
    float out = (hq == 0) ? s0 : (hq == 1) ? s1 : (hq == 2) ? s2 : s3;
    S[hq * 4194304 + tg * 2048 + vt + vl] = out;   // lane hq writes batch hq
    __syncthreads();                                // readers of buf^1 done
    if (it + 1 < 128) commit(cur ^ 1);
    __syncthreads();                                // writes visible
    cur ^= 1;
  }
}

// ---------------------------------------------------------------------------
// k2: online softmax over precomputed S + PV via bf16 MFMA.
// Block = (b, 32 t-rows). O accumulates in MFMA fp32 regs with alpha-rescale.
// ---------------------------------------------------------------------------
__global__ __launch_bounds__(256) void k2_softpv(
    const float* __restrict__ S, const unsigned short* __restrict__ vtw,
    float* __restrict__ O) {
  __shared__ float sl[2][32 * 68];            // S tile [32][64] pad 68
  __shared__ unsigned short vtl[2][64 * 72];  // Vt tile [h=64][v=64] pad 72
  __shared__ unsigned short ps[32 * 80];      // p bf16 [32][64] pad 80
  __shared__ float mrun[32], lrun[32], asc[32];
  const int tid = threadIdx.x;
  const int b = blockIdx.x >> 6, tt = blockIdx.x & 63;
  const int t0 = tt * 32;
  const int lane = tid & 63, wid = tid >> 6;
  const int mf = wid & 1, np = wid >> 1;
  const int r15 = lane & 15, u = lane >> 4;
  const int row = tid >> 3, vg = tid & 7;

  if (tid < 32) { mrun[tid] = -3.0e38f; lrun[tid] = 0.0f; }

  f32x4 stS[2], stV[2];
  auto issue = [&](int v0) {
#pragma unroll
    for (int i = 0; i < 2; ++i) {
      int c4 = i * 256 + tid;
      int pr = c4 >> 4, c = c4 & 15;
      stS[i] = *(const f32x4*)&S[b * 4194304 + (t0 + pr) * 2048 + v0 + c * 4];
    }
#pragma unroll
    for (int i = 0; i < 2; ++i) {
      int c8 = i * 256 + tid;
      int hr = c8 >> 3, cc = c8 & 7;
      stV[i] = *(const f32x4*)&vtw[(b * 64 + hr) * 2048 + v0 + cc * 8];
    }
  };
  auto commit = [&](int buf) {
#pragma unroll
    for (int i = 0; i < 2; ++i) {
      int c4 = i * 256 + tid;
      int pr = c4 >> 4, c = c4 & 15;
      *(f32x4*)&sl[buf][pr * 68 + c * 4] = stS[i];
    }
#pragma unroll
    for (int i = 0; i < 2; ++i) {
      int c8 = i * 256 + tid;
      int hr = c8 >> 3, cc = c8 & 7;
      *(f32x4*)&vtl[buf][hr * 72 + cc * 8] = stV[i];
    }
  };

  issue(0);
  commit(0);
  __syncthreads();

  f32x4 accA = {0.f, 0.f, 0.f, 0.f}, accB = accA;
  int cur = 0;
  for (int it = 0; it < 32; ++it) {
    if (it + 1 < 32) issue((it + 1) * 64);
    // ---- exp phase: thread = (row, 8-v group)
    f32x4 sa = *(const f32x4*)&sl[cur][row * 68 + vg * 8];
    f32x4 sb = *(const f32x4*)&sl[cur][row * 68 + vg * 8 + 4];
    float mx = fmaxf(fmaxf(fmaxf(sa[0], sa[1]), fmaxf(sa[2], sa[3])),
                     fmaxf(fmaxf(sb[0], sb[1]), fmaxf(sb[2], sb[3])));
    mx = fmaxf(mx, __shfl_xor(mx, 1));
    mx = fmaxf(mx, __shfl_xor(mx, 2));
    mx = fmaxf(mx, __shfl_xor(mx, 4));
    float mold = mrun[row];
    float mnew = fmaxf(mold, mx);
    float alpha = __expf(mold - mnew);
    f32x4 pa, pb;
#pragma unroll
    for (int c = 0; c < 4; ++c) {
      pa[c] = __expf(sa[c] - mnew);
      pb[c] = __expf(sb[c] - mnew);
    }
    float psum = pa[0] + pa[1] + pa[2] + pa[3] + pb[0] + pb[1] + pb[2] + pb[3];
    psum += __shfl_xor(psum, 1);
    psum += __shfl_xor(psum, 2);
    psum += __shfl_xor(psum, 4);
    if (vg == 0) {
      mrun[row] = mnew;
      lrun[row] = alpha * lrun[row] + psum;
      asc[row] = alpha;
    }
    u32x4 pw;
    pw[0] = (unsigned int)f2bf(pa[0]) | ((unsigned int)f2bf(pa[1]) << 16);
    pw[1] = (unsigned int)f2bf(pa[2]) | ((unsigned int)f2bf(pa[3]) << 16);
    pw[2] = (unsigned int)f2bf(pb[0]) | ((unsigned int)f2bf(pb[1]) << 16);
    pw[3] = (unsigned int)f2bf(pb[2]) | ((unsigned int)f2bf(pb[3]) << 16);
    *(u32x4*)&ps[row * 80 + vg * 8] = pw;
    __syncthreads();
    // ---- PV phase: rescale acc rows, then 2 k-steps of MFMA
    float al0 = asc[mf * 16 + u * 4 + 0];
    float al1 = asc[mf * 16 + u * 4 + 1];
    float al2 = asc[mf * 16 + u * 4 + 2];
    float al3 = asc[mf * 16 + u * 4 + 3];
    accA[0] *= al0; accA[1] *= al1; accA[2] *= al2; accA[3] *= al3;
    accB[0] *= al0; accB[1] *= al1; accB[2] *= al2; accB[3] *= al3;
#pragma unroll
    for (int ks = 0; ks < 2; ++ks) {
      bf16x8 af = *(const bf16x8*)&ps[(mf * 16 + r15) * 80 + ks * 32 + u * 8];
      bf16x8 b0 = *(const bf16x8*)&vtl[cur][(np * 32 + r15) * 72 + ks * 32 + u * 8];
      bf16x8 b1 = *(const bf16x8*)&vtl[cur][(np * 32 + 16 + r15) * 72 + ks * 32 + u * 8];
      accA = __builtin_amdgcn_mfma_f32_16x16x32_bf16(af, b0, accA, 0, 0, 0);
      accB = __builtin_amdgcn_mfma_f32_16x16x32_bf16(af, b1, accB, 0, 0, 0);
    }
    if (it + 1 < 32) commit(cur ^ 1);
    __syncthreads();
    cur ^= 1;
  }
  // epilogue: O row = t0 + mf*16 + u*4 + r, col = np*32 + (0|16) + r15
#pragma unroll
  for (int r = 0; r < 4; ++r) {
    float linv = 1.0f / lrun[mf * 16 + u * 4 + r];
    int trow = t0 + mf * 16 + u * 4 + r;
    O[((b << 11) + trow) * 64 + np * 32 + r15] = accA[r] * linv;
    O[((b << 11) + trow) * 64 + np * 32 + 16 + r15] = accB[r] * linv;
  }
}

// ---------------------------------------------------------------------------
extern "C" void kernel_launch(void* const* d_in, const int* in_sizes, int n_in,
                              void* d_out, int out_size, void* d_ws, size_t ws_size,
                              hipStream_t stream) {
  const float* x   = (const float*)d_in[0];
  const float* wq  = (const float*)d_in[1];
  const float* bq  = (const float*)d_in[2];
  const float* wk  = (const float*)d_in[3];
  const float* bk  = (const float*)d_in[4];
  const float* wv  = (const float*)d_in[5];
  const float* bv  = (const float*)d_in[6];
  const float* rel = (const float*)d_in[7];
  float* O = (float*)d_out;

  char* ws = (char*)d_ws;
  float* S             = (float*)(ws);                       // 67,108,864 B
  float* qw            = (float*)(ws + 67108864);            //  2,097,152 B
  float* k8w           = (float*)(ws + 69206016);            //  2,097,152 B
  unsigned short* vtw  = (unsigned short*)(ws + 71303168);   //  1,048,576 B
  unsigned short* wTh  = (unsigned short*)(ws + 72351744);   //    393,216 B
  unsigned short* wTl  = (unsigned short*)(ws + 72744960);   //    393,216 B
  // total ws usage: 73,138,176 bytes

  kconv_kernel<<<dim3(768), dim3(256), 0, stream>>>(wq, wk, wv, wTh, wTl);
  kproj_kernel<<<dim3(256), dim3(256), 0, stream>>>(x, wTh, wTl, bq, bk, bv, qw, k8w, vtw);
  k1_scores<<<dim3(512), dim3(256), 0, stream>>>(qw, k8w, rel, S);
  k2_softpv<<<dim3(256), dim3(256), 0, stream>>>(S, vtw, O);
}